// Round 3
// baseline (257.756 us; speedup 1.0000x reference)
//
#include <hip/hip_runtime.h>
#include <hip/hip_bf16.h>
#include <cstdint>

// Problem constants (fixed by the reference).
#define CDIM   256      // channels == code dim == K depth
#define NCODES 256
#define HWB    32768    // H*W = 128*256
#define BATCH  4
#define BN     128      // pixels per tile
#define NTILES 4        // px tiles per block (persistent blocks)
#define TPB    512      // 8 waves

typedef __bf16 bf16x8 __attribute__((ext_vector_type(8)));
typedef float  f32x4  __attribute__((ext_vector_type(4)));

// ---------------------------------------------------------------------------
// Fused prep: M[i][j] = sum_n (cb[n][i]/||cb_n||^2) * cb[n][j], bf16 out.
// ---------------------------------------------------------------------------
__global__ __launch_bounds__(256) void prep_kernel(const float* __restrict__ cb,
                                                   __bf16* __restrict__ Mb) {
    __shared__ float s[NCODES];
    const int i = blockIdx.x;
    const int j = threadIdx.x;

    const float* row = cb + (size_t)j * CDIM;
    float nrm = 0.f;
#pragma unroll 8
    for (int c = 0; c < CDIM; c += 4) {
        f32x4 v = *(const f32x4*)(row + c);
        nrm += v[0] * v[0] + v[1] * v[1] + v[2] * v[2] + v[3] * v[3];
    }
    s[j] = cb[(size_t)j * CDIM + i] / nrm;
    __syncthreads();

    float acc = 0.f;
#pragma unroll 16
    for (int n = 0; n < NCODES; ++n)
        acc += s[n] * cb[(size_t)n * CDIM + j];
    Mb[(size_t)i * CDIM + j] = (__bf16)acc;
}

// ---------------------------------------------------------------------------
// recon: out[b,c,p] = sum_k M[c][k] * feat[b,k,p].
//
// Structure (this round): M lives in REGISTERS -- wave w owns output rows
// w*32..w*32+31, full K=256 -> mreg[2][8] = 64 VGPRs/lane, loaded once per
// block (L2-hot).  Only the feature goes through LDS (transpose staging),
// double-buffered 2 x 8 KB.  Because no LDS data depends on vmcnt, the
// per-K-step barrier is a raw "s_waitcnt lgkmcnt(0); s_barrier" (one asm
// block, memory clobber => compiler cannot move LDS ops across it in either
// direction).  Feature loads (3-chunk-deep register pipeline, statically
// indexed fv[3][8]) stay IN FLIGHT across barriers -- the __syncthreads
// vmcnt(0) drain that capped rounds 0-2 is gone.
//
// Persistent blocks: grid = 256, each handles 4 tiles of 128 px (mreg loaded
// once).  In-flight/CU ~ 8 waves * 3 chunks * 2 KB = 48 KB > ~22 KB needed
// at 6.3 TB/s x 900 cy latency.
//
// B LDS swizzle: logical k-granule g of pixel-row px stored at granule
// q = g ^ ((px>>1)&3)  (16B granules, 64B rows).  Write side: wave covers all
// 8 bank-groups evenly (8 lanes x 4B per bank = conflict-free); read side
// (4 quads cover a full row) likewise balanced.
// ---------------------------------------------------------------------------
__global__ __launch_bounds__(TPB, 2) void recon_kernel(
    const float* __restrict__ feat, const __bf16* __restrict__ Mb,
    float* __restrict__ out) {
    __shared__ __align__(16) __bf16 Blds[2][BN * 32];   // 2 x 8 KB

    const int tid  = threadIdx.x;
    const int lane = tid & 63;
    const int w    = tid >> 6;       // wave 0..7
    const int quad = lane >> 4;      // 0..3
    const int l16  = lane & 15;
    const int r0   = w * 32;         // this wave's output-row base

    // ---- M fragments: A[row=r0+mt*16+l16][k=kc*32+quad*8+j], 64 VGPRs ------
    const __bf16* mb = Mb + (size_t)(r0 + l16) * CDIM + quad * 8;
    bf16x8 mreg[2][8];
#pragma unroll
    for (int mt = 0; mt < 2; ++mt)
#pragma unroll
        for (int kc = 0; kc < 8; ++kc)
            mreg[mt][kc] = *(const bf16x8*)(mb + (size_t)mt * 16 * CDIM + kc * 32);

    // ---- staging constants -------------------------------------------------
    const int spx   = lane + (w & 1) * 64;     // pixel row this thread stages
    const int sk0   = (w >> 1) * 8;            // k-row base this thread stages
    const int swoff = spx * 32 + (((w >> 1) ^ ((spx >> 1) & 3)) * 8);
    const int rdoff = (quad ^ ((l16 >> 1) & 3)) * 8;

    const int b        = blockIdx.x >> 6;          // 64 blocks per batch image
    const int px_base0 = (blockIdx.x & 63) * (BN * NTILES);

    const float* fB = feat + (size_t)b * CDIM * HWB;
    float*       oB = out  + (size_t)b * CDIM * HWB;

    for (int ti = 0; ti < NTILES; ++ti) {
        const int p0 = px_base0 + ti * BN;
        const float* fs = fB + p0 + spx + (size_t)sk0 * HWB;

        // ---- prologue: 3-deep register prefetch of chunks 0,1,2 ------------
        float fv[3][8];
#pragma unroll
        for (int c = 0; c < 3; ++c)
#pragma unroll
            for (int j = 0; j < 8; ++j)
                fv[c][j] = fs[(size_t)(c * 32 + j) * HWB];

        f32x4 acc[2][8];
#pragma unroll
        for (int mt = 0; mt < 2; ++mt)
#pragma unroll
            for (int nt = 0; nt < 8; ++nt)
                acc[mt][nt] = (f32x4){0.f, 0.f, 0.f, 0.f};

#pragma unroll
        for (int i = 0; i < 8; ++i) {
            // a: convert chunk i (loads issued 3 iters ago -> latency hidden)
            bf16x8 pk;
#pragma unroll
            for (int j = 0; j < 8; ++j) pk[j] = (__bf16)fv[i % 3][j];
            // b: reissue slot with chunk i+3 (stays in flight across barriers)
            if (i < 5) {
#pragma unroll
                for (int j = 0; j < 8; ++j)
                    fv[i % 3][j] = fs[(size_t)((i + 3) * 32 + j) * HWB];
            }
            // c: swizzled transpose-write of chunk i
            *(bf16x8*)(&Blds[i & 1][0] + swoff) = pk;
            // d: lgkm-only fence + barrier (vmcnt NOT drained)
            asm volatile("s_waitcnt lgkmcnt(0)\n\ts_barrier" ::: "memory");
            // e: MFMA chunk i
#pragma unroll
            for (int nt = 0; nt < 8; ++nt) {
                bf16x8 bfr = *(const bf16x8*)(
                    &Blds[i & 1][0] + (nt * 16 + l16) * 32 + rdoff);
                acc[0][nt] = __builtin_amdgcn_mfma_f32_16x16x32_bf16(
                    mreg[0][i], bfr, acc[0][nt], 0, 0, 0);
                acc[1][nt] = __builtin_amdgcn_mfma_f32_16x16x32_bf16(
                    mreg[1][i], bfr, acc[1][nt], 0, 0, 0);
            }
        }

        // ---- epilogue: D[row=quad*4+r][col=l16] per 16x16 tile -------------
        float* ob = oB + p0 + l16;
#pragma unroll
        for (int mt = 0; mt < 2; ++mt)
#pragma unroll
            for (int r = 0; r < 4; ++r) {
                float* orow = ob + (size_t)(r0 + mt * 16 + quad * 4 + r) * HWB;
#pragma unroll
                for (int nt = 0; nt < 8; ++nt)
                    orow[nt * 16] = acc[mt][nt][r];
            }
        // No extra barrier needed across tiles: next tile's first LDS write
        // (buf 0) is separated from this tile's last buf-0 reads (i=6) by the
        // i=7 fence, whose lgkmcnt(0) drained every wave's reads.
    }
}

// ---------------------------------------------------------------------------
extern "C" void kernel_launch(void* const* d_in, const int* in_sizes, int n_in,
                              void* d_out, int out_size, void* d_ws, size_t ws_size,
                              hipStream_t stream) {
    const float* feat = (const float*)d_in[0];   // [4,256,128,256] fp32
    const float* cb   = (const float*)d_in[1];   // [256,256] fp32
    float* out = (float*)d_out;

    __bf16* Mb = (__bf16*)d_ws;                  // 128 KB bf16 M

    prep_kernel<<<NCODES, 256, 0, stream>>>(cb, Mb);

    recon_kernel<<<256, TPB, 0, stream>>>(feat, Mb, out);   // persistent blocks
}

// Round 4
// 248.432 us; speedup vs baseline: 1.0375x; 1.0375x over previous
//
#include <hip/hip_runtime.h>
#include <hip/hip_bf16.h>
#include <cstdint>

// Problem constants (fixed by the reference).
#define CDIM   256      // channels == code dim == K depth
#define NCODES 256
#define HWB    32768    // H*W = 128*256
#define BATCH  4
#define BN     128      // pixels per block tile
#define TPB    512      // 8 waves
#define LROW   36       // LDS feature-tile row stride in bf16 (72 B = 9 x 8B)

typedef __bf16  bf16x8 __attribute__((ext_vector_type(8)));
typedef __bf16  bf16x2 __attribute__((ext_vector_type(2)));
typedef float   f32x4  __attribute__((ext_vector_type(4)));
typedef float   f32x2  __attribute__((ext_vector_type(2)));
typedef uint32_t u32x2 __attribute__((ext_vector_type(2)));
typedef uint32_t u32x4 __attribute__((ext_vector_type(4)));

// ---------------------------------------------------------------------------
// prep: Mpk[((k>>3)*256 + c)*8 + (k&7)] = M[c][k]  (bf16, b-frag-packed)
// where M[c][k] = sum_n (cb[n][c]/||cb_n||^2) * cb[n][k].
// 2 output rows (c) per block -> 2 fma per global load in the n-loop.
// ---------------------------------------------------------------------------
__global__ __launch_bounds__(256) void prep_kernel(const float* __restrict__ cb,
                                                   __bf16* __restrict__ Mpk) {
    __shared__ f32x2 s2[NCODES];
    const int i0 = blockIdx.x * 2;      // c rows i0, i0+1
    const int j  = threadIdx.x;         // k column

    const float* row = cb + (size_t)j * CDIM;
    float nrm = 0.f;
#pragma unroll 8
    for (int c = 0; c < CDIM; c += 4) {
        f32x4 v = *(const f32x4*)(row + c);
        nrm += v[0] * v[0] + v[1] * v[1] + v[2] * v[2] + v[3] * v[3];
    }
    const float inv = 1.0f / nrm;
    s2[j] = (f32x2){row[i0] * inv, row[i0 + 1] * inv};
    __syncthreads();

    f32x2 acc = {0.f, 0.f};
#pragma unroll 16
    for (int n = 0; n < NCODES; ++n) {
        const float cv = cb[(size_t)n * CDIM + j];
        const f32x2 sv = s2[n];
        acc[0] += sv[0] * cv;
        acc[1] += sv[1] * cv;
    }
    const int base = ((j >> 3) * 256) * 8 + (j & 7);
    Mpk[base + (size_t)(i0    ) * 8] = (__bf16)acc[0];
    Mpk[base + (size_t)(i0 + 1) * 8] = (__bf16)acc[1];
}

// ---------------------------------------------------------------------------
// recon: out[b,c,p] = sum_k M[c][k] * feat[b,k,p].
//
// Round-4 change: ALL global access is 16 B/lane (rounds 0-3 were 4 B/lane
// dwords on both loads and stores, which pins HBM at ~2.35 TB/s -- the
// scalar-access ceiling; three different schedules all plateaued there).
//
//  * Operands swapped vs rounds 0-3: A = feature (D rows = px), B = M
//    (D cols = c).  The f32x4 accumulator then holds 4 CONSECUTIVE px, so
//    the epilogue is global_store_dwordx4 (16 B/lane, 64 B segments/c-row).
//  * Feature loads are float4 (4 px of one k-row; 512 B/row/wave).  The
//    px<->k transpose happens at the LDS write: each thread packs bf16
//    pairs (k, k+1) and does 4x ds_write_b32 into a [px][k] tile.
//  * LDS row stride 72 B (9 x 8 B): fragment reads (2 x 8 B per a-frag)
//    map (l16,quad) -> bank-pair (9*l16 + 2*quad + o) & 15 -- every instr
//    moves 512 B in the minimum 4 beats (conflict-free).
//  * mreg: wave w owns c-range [w*32, w*32+32); b-frags for full K=256 in
//    64 VGPRs, loaded once per block from the packed Mpk (L2-hot).
//  * Keeps round-3's proven lgkm-only asm barrier (no vmcnt drain) and
//    2-deep register prefetch (2 float4 per thread per chunk in flight).
// ---------------------------------------------------------------------------
__global__ __launch_bounds__(TPB, 2) void recon_kernel(
    const float* __restrict__ feat, const __bf16* __restrict__ Mpk,
    float* __restrict__ out) {
    __shared__ __align__(16) __bf16 Blds[2][BN * LROW];   // 2 x 9216 B

    const int tid  = threadIdx.x;
    const int lane = tid & 63;
    const int w    = tid >> 6;       // wave 0..7
    const int quad = lane >> 4;      // 0..3
    const int l16  = lane & 15;
    const int c0   = w * 32;         // this wave's output-channel base

    // ---- b-frag registers: mreg[ct][kc] = M[c0+ct*16+l16][kc*32+quad*8+j] --
    bf16x8 mreg[2][8];
#pragma unroll
    for (int ct = 0; ct < 2; ++ct)
#pragma unroll
        for (int kc = 0; kc < 8; ++kc)
            mreg[ct][kc] = *(const bf16x8*)(
                Mpk + (size_t)((kc * 4 + quad) * 256 + c0 + ct * 16 + l16) * 8);

    const int b  = blockIdx.x >> 8;          // 256 px-tiles per batch image
    const int p0 = (blockIdx.x & 255) * BN;

    // ---- staging: thread -> (k-pair kp, px-quad px4) -----------------------
    const int px4 = tid & 31;                // 4*px4 = first of 4 px
    const int kp  = tid >> 5;                // k = 2*kp (0..30)
    const float* f0 = feat + (size_t)b * CDIM * HWB + p0 + px4 * 4;

    f32x4 acc[8][2];
#pragma unroll
    for (int mt = 0; mt < 8; ++mt)
#pragma unroll
        for (int ct = 0; ct < 2; ++ct)
            acc[mt][ct] = (f32x4){0.f, 0.f, 0.f, 0.f};

    // ---- prologue: prefetch chunks 0,1 into registers ----------------------
    f32x4 fva[2], fvb[2];                    // [slot] even-k row, odd-k row
#pragma unroll
    for (int s = 0; s < 2; ++s) {
        fva[s] = *(const f32x4*)(f0 + (size_t)(s * 32 + 2 * kp) * HWB);
        fvb[s] = *(const f32x4*)(f0 + (size_t)(s * 32 + 2 * kp + 1) * HWB);
    }

    const int rbase = l16 * 18 + quad * 4;   // a-frag u32 index within row set

#pragma unroll
    for (int i = 0; i < 8; ++i) {
        const int sl = i & 1;
        // -- pack + transpose-write chunk i (loads issued 2 iters ago) -------
        __bf16* wb = &Blds[i & 1][0] + (px4 * 4) * LROW + 2 * kp;
#pragma unroll
        for (int e = 0; e < 4; ++e) {
            bf16x2 p;
            p[0] = (__bf16)fva[sl][e];
            p[1] = (__bf16)fvb[sl][e];
            *(bf16x2*)(wb + (size_t)e * LROW) = p;
        }
        // -- issue loads for chunk i+2 (stay in flight across barriers) ------
        if (i < 6) {
            fva[sl] = *(const f32x4*)(f0 + (size_t)((i + 2) * 32 + 2 * kp) * HWB);
            fvb[sl] = *(const f32x4*)(f0 + (size_t)((i + 2) * 32 + 2 * kp + 1) * HWB);
        }
        // -- lgkm-only fence + barrier (vmcnt NOT drained) -------------------
        asm volatile("s_waitcnt lgkmcnt(0)\n\ts_barrier" ::: "memory");
        // -- MFMA chunk i: af[px-tile mt] x mreg[ct][i] ----------------------
        const uint32_t* lr = (const uint32_t*)(&Blds[i & 1][0]);
#pragma unroll
        for (int mt = 0; mt < 8; ++mt) {
            u32x2 lo = *(const u32x2*)(lr + rbase + mt * 288);
            u32x2 hi = *(const u32x2*)(lr + rbase + mt * 288 + 2);
            bf16x8 af = __builtin_bit_cast(bf16x8, (u32x4){lo[0], lo[1], hi[0], hi[1]});
            acc[mt][0] = __builtin_amdgcn_mfma_f32_16x16x32_bf16(
                af, mreg[0][i], acc[mt][0], 0, 0, 0);
            acc[mt][1] = __builtin_amdgcn_mfma_f32_16x16x32_bf16(
                af, mreg[1][i], acc[mt][1], 0, 0, 0);
        }
    }

    // ---- epilogue: D rows = px -> f32x4 stores (16 B/lane) -----------------
    float* ob = out + (size_t)b * CDIM * HWB + p0 + quad * 4;
#pragma unroll
    for (int mt = 0; mt < 8; ++mt)
#pragma unroll
        for (int ct = 0; ct < 2; ++ct)
            *(f32x4*)(ob + (size_t)(c0 + ct * 16 + l16) * HWB + mt * 16) =
                acc[mt][ct];
}

// ---------------------------------------------------------------------------
extern "C" void kernel_launch(void* const* d_in, const int* in_sizes, int n_in,
                              void* d_out, int out_size, void* d_ws, size_t ws_size,
                              hipStream_t stream) {
    const float* feat = (const float*)d_in[0];   // [4,256,128,256] fp32
    const float* cb   = (const float*)d_in[1];   // [256,256] fp32
    float* out = (float*)d_out;

    __bf16* Mpk = (__bf16*)d_ws;                 // 128 KB packed bf16 M

    prep_kernel<<<NCODES / 2, 256, 0, stream>>>(cb, Mpk);

    const int nblocks = BATCH * (HWB / BN);      // 1024
    recon_kernel<<<nblocks, TPB, 0, stream>>>(feat, Mpk, out);
}

// Round 6
// 240.414 us; speedup vs baseline: 1.0721x; 1.0333x over previous
//
#include <hip/hip_runtime.h>
#include <hip/hip_bf16.h>
#include <cstdint>

// Problem constants (fixed by the reference).
#define CDIM   256      // channels == code dim == K depth
#define NCODES 256
#define HWB    32768    // H*W = 128*256
#define BATCH  4
#define BN     256      // pixels per block tile (widened: 1 KB bursts per row)
#define TPB    512      // 8 waves
#define LROW   36       // LDS feature-tile row stride in bf16 (72 B = 9 x 8B)

typedef __bf16  bf16x8 __attribute__((ext_vector_type(8)));
typedef __bf16  bf16x4 __attribute__((ext_vector_type(4)));
typedef float   f32x4  __attribute__((ext_vector_type(4)));
typedef float   f32x2  __attribute__((ext_vector_type(2)));

// ---------------------------------------------------------------------------
// prep: Mpk[((k>>3)*256 + c)*8 + (k&7)] = M[c][k]  (bf16, b-frag-packed)
// where M[c][k] = sum_n (cb[n][c]/||cb_n||^2) * cb[n][k].
// ---------------------------------------------------------------------------
__global__ __launch_bounds__(256) void prep_kernel(const float* __restrict__ cb,
                                                   __bf16* __restrict__ Mpk) {
    __shared__ f32x2 s2[NCODES];
    const int i0 = blockIdx.x * 2;      // c rows i0, i0+1
    const int j  = threadIdx.x;         // k column

    const float* row = cb + (size_t)j * CDIM;
    float nrm = 0.f;
#pragma unroll 8
    for (int c = 0; c < CDIM; c += 4) {
        f32x4 v = *(const f32x4*)(row + c);
        nrm += v[0] * v[0] + v[1] * v[1] + v[2] * v[2] + v[3] * v[3];
    }
    const float inv = 1.0f / nrm;
    s2[j] = (f32x2){row[i0] * inv, row[i0 + 1] * inv};
    __syncthreads();

    f32x2 acc = {0.f, 0.f};
#pragma unroll 16
    for (int n = 0; n < NCODES; ++n) {
        const float cv = cb[(size_t)n * CDIM + j];
        const f32x2 sv = s2[n];
        acc[0] += sv[0] * cv;
        acc[1] += sv[1] * cv;
    }
    const int base = ((j >> 3) * 256) * 8 + (j & 7);
    Mpk[base + (size_t)(i0    ) * 8] = (__bf16)acc[0];
    Mpk[base + (size_t)(i0 + 1) * 8] = (__bf16)acc[1];
}

// ---------------------------------------------------------------------------
// recon: out[b,c,p] = sum_k M[c][k] * feat[b,k,p].
//
// Round-5 memory-path experiment (schedule held at the round-3/4 proven
// structure: mreg-resident M, lgkm-only barriers, reg prefetch):
//  * BN 128 -> 256: every k-row read burst and c-row write segment doubles
//    (512 B -> 1 KB), spanning 2x the L2 sets under the 2^17-byte row
//    stride that all rounds 0-4 shared (the schedule-insensitive ~2.5 TB/s
//    plateau points at DRAM/L2-path pathology, not scheduling).
//  * Feature loads are __builtin_nontemporal_load (each line read exactly
//    once globally -> evict-first; attacks the L1/L2 allocation path).
//    Stores stay normal: L2 write-merging is proven (WRITE_SIZE exact).
//
// Wave w owns c-range [w*32, w*32+32) x all 256 px: acc[16][2] f32x4 (128
// regs, expected in AGPRs), mreg[2][8] (64 VGPRs).  ~244 unified regs ->
// 2 waves/SIMD, 1 block/CU -- acceptable: rounds 0-4 proved occupancy and
// scheduling do not move this kernel.
// ---------------------------------------------------------------------------
__global__ __launch_bounds__(TPB, 2) void recon_kernel(
    const float* __restrict__ feat, const __bf16* __restrict__ Mpk,
    float* __restrict__ out) {
    __shared__ __align__(16) __bf16 Blds[2][BN * LROW];   // 2 x 18432 B

    const int tid  = threadIdx.x;
    const int lane = tid & 63;
    const int w    = tid >> 6;       // wave 0..7
    const int quad = lane >> 4;      // 0..3
    const int l16  = lane & 15;
    const int c0   = w * 32;         // this wave's output-channel base

    // ---- b-frag registers: mreg[ct][kc] = M[c0+ct*16+l16][kc*32+quad*8+j] --
    bf16x8 mreg[2][8];
#pragma unroll
    for (int ct = 0; ct < 2; ++ct)
#pragma unroll
        for (int kc = 0; kc < 8; ++kc)
            mreg[ct][kc] = *(const bf16x8*)(
                Mpk + (size_t)((kc * 4 + quad) * 256 + c0 + ct * 16 + l16) * 8);

    const int b  = blockIdx.x >> 7;          // 128 px-tiles per batch image
    const int p0 = (blockIdx.x & 127) * BN;

    // ---- staging: thread -> (k-quad kq, px-quad px4) -----------------------
    const int px4 = tid & 63;                // 4*px4 = first of 4 px
    const int kq  = tid >> 6;                // k rows 4kq..4kq+3 (0..28)
    const float* f0 = feat + (size_t)b * CDIM * HWB + p0 + px4 * 4;

    f32x4 acc[16][2];
#pragma unroll
    for (int mt = 0; mt < 16; ++mt)
#pragma unroll
        for (int ct = 0; ct < 2; ++ct)
            acc[mt][ct] = (f32x4){0.f, 0.f, 0.f, 0.f};

    // ---- prologue: prefetch chunk 0 (4 consecutive k-rows, nontemporal) ----
    f32x4 L[2][4];                           // [slot][k-sub-row]
#pragma unroll
    for (int r = 0; r < 4; ++r)
        L[0][r] = __builtin_nontemporal_load(
            (const f32x4*)(f0 + (size_t)(4 * kq + r) * HWB));

#pragma unroll
    for (int i = 0; i < 8; ++i) {
        const int sl = i & 1;
        // -- issue chunk i+1 loads first (in flight across the barrier) ------
        if (i < 7) {
            const float* fn = f0 + (size_t)((i + 1) * 32 + 4 * kq) * HWB;
#pragma unroll
            for (int r = 0; r < 4; ++r)
                L[sl ^ 1][r] = __builtin_nontemporal_load(
                    (const f32x4*)(fn + (size_t)r * HWB));
        }
        // -- pack + transpose-write chunk i: per px-row e, cols 4kq..4kq+3 ---
        __bf16* wb = &Blds[sl][0] + (px4 * 4) * LROW + 4 * kq;
#pragma unroll
        for (int e = 0; e < 4; ++e) {
            bf16x4 p;
            p[0] = (__bf16)L[sl][0][e];
            p[1] = (__bf16)L[sl][1][e];
            p[2] = (__bf16)L[sl][2][e];
            p[3] = (__bf16)L[sl][3][e];
            *(bf16x4*)(wb + (size_t)e * LROW) = p;
        }
        // -- lgkm-only fence + barrier (vmcnt NOT drained) -------------------
        asm volatile("s_waitcnt lgkmcnt(0)\n\ts_barrier" ::: "memory");
        // -- MFMA chunk i ----------------------------------------------------
#pragma unroll
        for (int mt = 0; mt < 16; ++mt) {
            bf16x8 af = *(const bf16x8*)(
                &Blds[sl][0] + (mt * 16 + l16) * LROW + quad * 8);
            acc[mt][0] = __builtin_amdgcn_mfma_f32_16x16x32_bf16(
                af, mreg[0][i], acc[mt][0], 0, 0, 0);
            acc[mt][1] = __builtin_amdgcn_mfma_f32_16x16x32_bf16(
                af, mreg[1][i], acc[mt][1], 0, 0, 0);
        }
    }

    // ---- epilogue: D rows = px -> f32x4 stores (16 B/lane) -----------------
    float* ob = out + (size_t)b * CDIM * HWB + p0 + quad * 4;
#pragma unroll
    for (int mt = 0; mt < 16; ++mt)
#pragma unroll
        for (int ct = 0; ct < 2; ++ct)
            *(f32x4*)(ob + (size_t)(c0 + ct * 16 + l16) * HWB + mt * 16) =
                acc[mt][ct];
}

// ---------------------------------------------------------------------------
extern "C" void kernel_launch(void* const* d_in, const int* in_sizes, int n_in,
                              void* d_out, int out_size, void* d_ws, size_t ws_size,
                              hipStream_t stream) {
    const float* feat = (const float*)d_in[0];   // [4,256,128,256] fp32
    const float* cb   = (const float*)d_in[1];   // [256,256] fp32
    float* out = (float*)d_out;

    __bf16* Mpk = (__bf16*)d_ws;                 // 128 KB packed bf16 M

    prep_kernel<<<NCODES / 2, 256, 0, stream>>>(cb, Mpk);

    const int nblocks = BATCH * (HWB / BN);      // 512
    recon_kernel<<<nblocks, TPB, 0, stream>>>(feat, Mpk, out);
}